// Round 5
// baseline (826.561 us; speedup 1.0000x reference)
//
#include <hip/hip_runtime.h>
#include <cstdint>
#include <cstddef>

#define BB 4
#define NN 8192
#define MM 2048
#define KK 16
#define DP 128
#define DM 256
#define QROW 131  // 3 + 128 floats per query row

typedef __attribute__((ext_vector_type(8))) short short8;
typedef __attribute__((ext_vector_type(4))) float floatx4;

__device__ __forceinline__ unsigned short f2bf(float x) {
  unsigned u = __float_as_uint(x);
  unsigned r = (u + 0x7FFFu + ((u >> 16) & 1u)) >> 16;   // RNE
  return (unsigned short)r;
}

// Deterministic distance->sortable-key. Same DAG as r2-r4 (harness-verified):
// orders identically to the reference dist for selection purposes.
__device__ __forceinline__ unsigned dkey(float qx, float qy, float qz, float q2,
                                         float xx, float xy, float xz, float x2) {
  float cr = fmaf(qz, xz, fmaf(qy, xy, qx * xx));
  float d  = fmaf(-2.0f, cr, q2 + x2);
  unsigned u = __float_as_uint(d);
  return (u & 0x80000000u) ? ~u : (u | 0x80000000u);  // ascending-sortable
}

// ---------------------------------------------------------------------------
// Kernel 0: weights f32->bf16, transposed to [N][K] (k-contig) back-to-back.
// wk stored NEGATED so fused computes a = (q + pe) + x@(-wk) in one MFMA
// accumulation (bounds concurrent accumulators; pe dies into the a-init).
// ---------------------------------------------------------------------------
__global__ __launch_bounds__(256) void prep_weights(
    const float* __restrict__ wq, const float* __restrict__ fc1,
    const float* __restrict__ wk, const float* __restrict__ wv,
    const float* __restrict__ d2, const float* __restrict__ g1,
    const float* __restrict__ g2, const float* __restrict__ fc2,
    unsigned short* __restrict__ dst)
{
  long e = (long)blockIdx.x * 256 + threadIdx.x;
  if (e >= 425984) return;
  const float* src; int sh; int Nmat; long off; bool neg = false;
  if (e < 32768)       { src = wq;  sh = 7; Nmat = 256; off = 0; }
  else if (e < 65536)  { src = fc1; sh = 7; Nmat = 256; off = 32768; }
  else if (e < 131072) { src = wk;  sh = 8; Nmat = 256; off = 65536; neg = true; }
  else if (e < 196608) { src = wv;  sh = 8; Nmat = 256; off = 131072; }
  else if (e < 262144) { src = d2;  sh = 8; Nmat = 256; off = 196608; }
  else if (e < 327680) { src = g1;  sh = 8; Nmat = 256; off = 262144; }
  else if (e < 393216) { src = g2;  sh = 8; Nmat = 256; off = 327680; }
  else                 { src = fc2; sh = 8; Nmat = 128; off = 393216; }
  long d = e - off;
  int K = 1 << sh;
  int n = (int)(d >> sh), k = (int)(d & (K - 1));
  float v = src[(long)k * Nmat + n];
  dst[e] = f2bf(neg ? -v : v);
}

// ---------------------------------------------------------------------------
// Kernel 1: exact KNN (k=16) — REGISTER INSERTION-SORT version.
// No LDS, no atomics, no barriers, no sample/threshold, no fallback.
// One wave serves TWO queries (point loads amortized 2x). Each lane keeps a
// sorted 16-deep array of (key<<32|idx) composites per query; insertion is a
// fully-static predicated shift (no scratch). Lane sees 128 points >= 16, so
// the union of per-lane top-16 contains the global top-16 => EXACT, with
// composite order == jax.lax.top_k tie semantics (smallest idx first).
// Loads: 3 x dwordx4 per 4 points (16 B/lane coalescing sweet spot).
// Grid 1024x256 -> 16 waves/CU, all resident, balanced.
// ---------------------------------------------------------------------------
__device__ __forceinline__ void ins16(unsigned long long (&t)[16],
                                      unsigned long long c) {
  if (__any(c < t[15])) {
    #pragma unroll
    for (int j = 15; j >= 1; --j)
      t[j] = (c < t[j-1]) ? t[j-1] : ((c < t[j]) ? c : t[j]);
    t[0] = (c < t[0]) ? c : t[0];
  }
}

__global__ __launch_bounds__(256, 4) void knn_kernel(
    const float* __restrict__ xyz, const float* __restrict__ query,
    int* __restrict__ knn_out)
{
  const int tid = threadIdx.x;
  const int l = tid & 63, w = tid >> 6;
  const int qbase = (blockIdx.x * 4 + w) * 2;   // two queries per wave
  const int b = qbase >> 11;                    // pairs never straddle batches
  const float* X = xyz + (size_t)b * NN * 3;

  float qx[2], qy[2], qz[2], q2[2];
  #pragma unroll
  for (int q = 0; q < 2; ++q) {
    const float* qp = query + (size_t)(qbase + q) * QROW;
    qx[q] = qp[0]; qy[q] = qp[1]; qz[q] = qp[2];
    q2[q] = fmaf(qz[q], qz[q], fmaf(qy[q], qy[q], qx[q] * qx[q]));
  }

  unsigned long long t0[16], t1[16];
  #pragma unroll
  for (int i = 0; i < 16; ++i) { t0[i] = ~0ull; t1[i] = ~0ull; }

  for (int it = 0; it < NN / 256; ++it) {       // 32 iterations
    int p0 = it * 256 + l * 4;                  // 4 points per lane
    const float4* P = (const float4*)(X + 3 * p0);   // 16-B aligned
    float4 A = P[0], Bv = P[1], C = P[2];
    float px[4] = {A.x, A.w, Bv.z, C.y};
    float py[4] = {A.y, Bv.x, Bv.w, C.z};
    float pz[4] = {A.z, Bv.y, C.x, C.w};
    #pragma unroll
    for (int j = 0; j < 4; ++j) {
      float x2 = fmaf(pz[j], pz[j], fmaf(py[j], py[j], px[j] * px[j]));
      unsigned idx = (unsigned)(p0 + j);
      unsigned u0 = dkey(qx[0], qy[0], qz[0], q2[0], px[j], py[j], pz[j], x2);
      ins16(t0, ((unsigned long long)u0 << 32) | idx);
      unsigned u1 = dkey(qx[1], qy[1], qz[1], q2[1], px[j], py[j], pz[j], x2);
      ins16(t1, ((unsigned long long)u1 << 32) | idx);
    }
  }

  // ---- merge: 16 rounds of butterfly-min + owner shift-down, per query ----
  #pragma unroll
  for (int q = 0; q < 2; ++q) {
    for (int r = 0; r < KK; ++r) {
      unsigned long long m = q == 0 ? t0[0] : t1[0];
      #pragma unroll
      for (int d = 32; d >= 1; d >>= 1) {
        unsigned long long o = __shfl_xor(m, d, 64);
        m = o < m ? o : m;
      }
      if (l == 0) knn_out[(qbase + q) * KK + r] = (int)(unsigned)(m & 0xffffffffu);
      if (q == 0) {
        bool own = (t0[0] == m);
        #pragma unroll
        for (int j = 0; j < 15; ++j) t0[j] = own ? t0[j+1] : t0[j];
        if (own) t0[15] = ~0ull;
      } else {
        bool own = (t1[0] == m);
        #pragma unroll
        for (int j = 0; j < 15; ++j) t1[j] = own ? t1[j+1] : t1[j];
        if (own) t1[15] = ~0ull;
      }
    }
  }
}

// ---------------------------------------------------------------------------
// Balanced MFMA tile-GEMM helper. ks-loop at UNROLL 2 bounds in-flight
// staging registers (full unroll -> scheduler hoists ~32 global loads ->
// spill; proven r2->r3: WRITE 352->185 MB).
// ---------------------------------------------------------------------------
template<int KT, int RT>
__device__ __forceinline__ void gemm_tiles(
    const unsigned short* aBase, int aStride,
    const unsigned short* __restrict__ bT,
    int lm, int lq, int colBase, int rtBase, floatx4 (&acc)[RT][4])
{
  const unsigned short* aRow = aBase + (rtBase*16 + lm)*aStride + lq*8;
  const unsigned short* bRow = bT + (size_t)(colBase + lm)*(KT*32) + lq*8;
  #pragma unroll 2
  for (int ks = 0; ks < KT; ++ks) {
    short8 af[RT];
    #pragma unroll
    for (int rt = 0; rt < RT; ++rt)
      af[rt] = *(const short8*)&aRow[rt*16*aStride + ks*32];
    short8 bf[4];
    #pragma unroll
    for (int c = 0; c < 4; ++c)
      bf[c] = *(const short8*)&bRow[(size_t)c*16*(KT*32) + ks*32];
    #pragma unroll
    for (int rt = 0; rt < RT; ++rt)
      #pragma unroll
      for (int c = 0; c < 4; ++c)
        acc[rt][c] = __builtin_amdgcn_mfma_f32_16x16x32_bf16(af[rt], bf[c], acc[rt][c], 0, 0, 0);
  }
}

// ---------------------------------------------------------------------------
// Kernel 2: fused block, 4 queries (64 rows) per 256-thread WG, 2 blocks/CU.
// Unchanged from r4 (271 us, VGPR=100, no bulk spill).
// ---------------------------------------------------------------------------
__global__ __launch_bounds__(256, 2) void fused_mfma(
    const float* __restrict__ xyz, const float* __restrict__ features,
    const float* __restrict__ query,
    const float* __restrict__ fc1_b, const float* __restrict__ fc2_b,
    const float* __restrict__ d1_w,  const float* __restrict__ d1_b,
    const float* __restrict__ d2_b,
    const float* __restrict__ g1_b,  const float* __restrict__ g2_b,
    const unsigned short* __restrict__ wT,
    const int* __restrict__ knn_idx,
    float* __restrict__ out_res, float* __restrict__ out_attn)
{
  const unsigned short* wq_t  = wT;
  const unsigned short* fc1_t = wT + 32768;
  const unsigned short* wkN_t = wT + 65536;    // negated
  const unsigned short* wv_t  = wT + 131072;
  const unsigned short* d2_t  = wT + 196608;
  const unsigned short* g1_t  = wT + 262144;
  const unsigned short* g2_t  = wT + 327680;
  const unsigned short* fc2_t = wT + 393216;

  __shared__ alignas(16) unsigned short bufA[64*264];  // feat(136) / h1 / a / rm
  __shared__ alignas(16) unsigned short bufB[64*264];  // x / h
  __shared__ alignas(16) unsigned short s_qf[16*136];  // query_f bf16 (rows 0..3)
  __shared__ alignas(16) float s_q[4*256];             // q projection (f32)
  __shared__ float s_delta[64][4];
  __shared__ int   s_idx[64];

  const int tid = threadIdx.x;
  const int l  = tid & 63, w = tid >> 6;
  const int lm = l & 15,  lq = l >> 4;
  const int colBase = w * 64;
  const int bm0 = blockIdx.x << 2;
  const int b   = bm0 >> 11;

  // ---- Phase 0: indices, delta, query_f, feature gather ----
  if (tid < 64) {
    int q = tid >> 4, n = tid & 15;
    int idx = knn_idx[(bm0 + q)*KK + n];
    s_idx[tid] = idx;
    const float* qp = query + (size_t)(bm0 + q) * QROW;
    const float* xp = xyz + ((size_t)b*NN + idx)*3;
    s_delta[tid][0] = qp[0] - xp[0];
    s_delta[tid][1] = qp[1] - xp[1];
    s_delta[tid][2] = qp[2] - xp[2];
  }
  {
    int e = tid * 2;                    // 512 elems: rows 0..3 x 128 cols
    int q = e >> 7, c = e & 127;
    const float* qp = query + (size_t)(bm0 + q)*QROW + 3 + c;
    unsigned v = ((unsigned)f2bf(qp[1]) << 16) | f2bf(qp[0]);
    *(unsigned*)&s_qf[q*136 + c] = v;
  }
  __syncthreads();
  {
    int r = tid >> 2, c0 = (tid & 3) * 32;
    const float4* fp4 = (const float4*)(features + ((size_t)b*NN + s_idx[r])*DP + c0);
    unsigned short* dst = &bufA[r*136 + c0];
    #pragma unroll
    for (int i = 0; i < 8; ++i) {
      float4 v4 = fp4[i];
      *(unsigned*)&dst[i*4]     = ((unsigned)f2bf(v4.y) << 16) | f2bf(v4.x);
      *(unsigned*)&dst[i*4 + 2] = ((unsigned)f2bf(v4.w) << 16) | f2bf(v4.z);
    }
  }
  __syncthreads();

  const floatx4 zero4 = {0.f, 0.f, 0.f, 0.f};

  // ---- Phase 1: x = feat @ fc1 + b  -> bufB ;  q = qf @ wq -> s_q ----
  {
    floatx4 acc[4][4];
    #pragma unroll
    for (int rt = 0; rt < 4; ++rt)
      #pragma unroll
      for (int c = 0; c < 4; ++c) acc[rt][c] = zero4;
    gemm_tiles<4,4>(bufA, 136, fc1_t, lm, lq, colBase, 0, acc);
    #pragma unroll
    for (int c = 0; c < 4; ++c) {
      float bias = fc1_b[colBase + c*16 + lm];
      #pragma unroll
      for (int rt = 0; rt < 4; ++rt)
        #pragma unroll
        for (int r = 0; r < 4; ++r)
          bufB[(rt*16 + lq*4 + r)*264 + colBase + c*16 + lm] = f2bf(acc[rt][c][r] + bias);
    }
  }
  {
    floatx4 qa[1][4];
    #pragma unroll
    for (int c = 0; c < 4; ++c) qa[0][c] = zero4;
    gemm_tiles<4,1>(s_qf, 136, wq_t, lm, lq, colBase, 0, qa);
    if (lq == 0) {
      #pragma unroll
      for (int c = 0; c < 4; ++c)
        #pragma unroll
        for (int r = 0; r < 4; ++r)
          s_q[r*256 + colBase + c*16 + lm] = qa[0][c][r];   // row r == query r
    }
  }
  __syncthreads();   // x visible; bufA(feat) dead

  // ---- Phase 2: h1 = relu(delta @ d1 + b) -> bufA (VALU, tiny K=3) ----
  {
    int c = tid;
    float w0 = d1_w[c], w1 = d1_w[256 + c], w2 = d1_w[512 + c], bb = d1_b[c];
    #pragma unroll 4
    for (int r = 0; r < 64; ++r) {
      float v = fmaf(s_delta[r][2], w2, fmaf(s_delta[r][1], w1,
                fmaf(s_delta[r][0], w0, bb)));
      bufA[r*264 + c] = f2bf(v > 0.f ? v : 0.f);
    }
  }
  __syncthreads();   // h1 visible

  // ---- Phase 3: pe = h1 @ d2 + b (regs; acc set #1) ----
  floatx4 pe[4][4];
  #pragma unroll
  for (int rt = 0; rt < 4; ++rt)
    #pragma unroll
    for (int c = 0; c < 4; ++c) pe[rt][c] = zero4;
  gemm_tiles<8,4>(bufA, 264, d2_t, lm, lq, colBase, 0, pe);
  #pragma unroll
  for (int c = 0; c < 4; ++c) {
    float bias = d2_b[colBase + c*16 + lm];
    #pragma unroll
    for (int rt = 0; rt < 4; ++rt)
      #pragma unroll
      for (int r = 0; r < 4; ++r) pe[rt][c][r] += bias;
  }

  // ---- Phase 4: vpe = x @ wv + pe (acc set #2 initialized from pe) ----
  floatx4 vpe[4][4];
  #pragma unroll
  for (int rt = 0; rt < 4; ++rt)
    #pragma unroll
    for (int c = 0; c < 4; ++c) vpe[rt][c] = pe[rt][c];
  gemm_tiles<8,4>(bufB, 264, wv_t, lm, lq, colBase, 0, vpe);
  __syncthreads();   // all waves done reading bufA(h1); a-writes may begin

  // ---- Phase 5: a = (q + pe) + x @ (-wk) -> bufA ; pe dies in the init ----
  {
    floatx4 acc[4][4];
    #pragma unroll
    for (int rt = 0; rt < 4; ++rt)
      #pragma unroll
      for (int c = 0; c < 4; ++c) {
        float qv = s_q[rt*256 + colBase + c*16 + lm];
        #pragma unroll
        for (int r = 0; r < 4; ++r) acc[rt][c][r] = qv + pe[rt][c][r];
      }
    gemm_tiles<8,4>(bufB, 264, wkN_t, lm, lq, colBase, 0, acc);
    #pragma unroll
    for (int rt = 0; rt < 4; ++rt)
      #pragma unroll
      for (int c = 0; c < 4; ++c)
        #pragma unroll
        for (int r = 0; r < 4; ++r)
          bufA[(rt*16 + lq*4 + r)*264 + colBase + c*16 + lm] = f2bf(acc[rt][c][r]);
  }
  __syncthreads();   // a visible; bufB(x) dead

  // ---- Phase 6: h = relu(a @ g1 + b) -> bufB ----
  {
    floatx4 h[4][4];
    #pragma unroll
    for (int rt = 0; rt < 4; ++rt)
      #pragma unroll
      for (int c = 0; c < 4; ++c) h[rt][c] = zero4;
    gemm_tiles<8,4>(bufA, 264, g1_t, lm, lq, colBase, 0, h);
    #pragma unroll
    for (int c = 0; c < 4; ++c) {
      float bias = g1_b[colBase + c*16 + lm];
      #pragma unroll
      for (int rt = 0; rt < 4; ++rt)
        #pragma unroll
        for (int r = 0; r < 4; ++r) {
          float v = h[rt][c][r] + bias;
          bufB[(rt*16 + lq*4 + r)*264 + colBase + c*16 + lm] = f2bf(v > 0.f ? v : 0.f);
        }
    }
  }
  __syncthreads();   // h visible; bufA(a) dead -> reuse as s_rm

  // ---- Phase 7/8: lg = h @ g2 + b (all rt in ONE gemm: B loaded once),
  //      softmax over neighbors, NT attn store, rm = sum_n attn * vpe ----
  unsigned short* s_rm = bufA;   // [16][264], rows 0..3 valid
  {
    floatx4 lg[4][4];
    #pragma unroll
    for (int rt = 0; rt < 4; ++rt)
      #pragma unroll
      for (int c = 0; c < 4; ++c) lg[rt][c] = zero4;
    gemm_tiles<8,4>(bufB, 264, g2_t, lm, lq, colBase, 0, lg);
    #pragma unroll
    for (int rt = 0; rt < 4; ++rt) {
      #pragma unroll
      for (int c = 0; c < 4; ++c) {
        float bias = g2_b[colBase + c*16 + lm];
        float v[4];
        float mx = -INFINITY;
        #pragma unroll
        for (int r = 0; r < 4; ++r) {
          v[r] = (lg[rt][c][r] + bias) * 0.0625f;
          mx = fmaxf(mx, v[r]);
        }
        mx = fmaxf(mx, __shfl_xor(mx, 16, 64));
        mx = fmaxf(mx, __shfl_xor(mx, 32, 64));
        float s = 0.f;
        #pragma unroll
        for (int r = 0; r < 4; ++r) { v[r] = __expf(v[r] - mx); s += v[r]; }
        s += __shfl_xor(s, 16, 64);
        s += __shfl_xor(s, 32, 64);
        float inv = 1.0f / s;
        float rm = 0.f;
        size_t abase = ((size_t)(bm0 + rt)*KK)*DM + colBase + c*16 + lm;
        #pragma unroll
        for (int r = 0; r < 4; ++r) {
          float at = v[r] * inv;
          __builtin_nontemporal_store(at, &out_attn[abase + (size_t)(lq*4 + r)*DM]);
          rm = fmaf(at, vpe[rt][c][r], rm);
        }
        rm += __shfl_xor(rm, 16, 64);
        rm += __shfl_xor(rm, 32, 64);
        if (lq == 0) s_rm[rt*264 + colBase + c*16 + lm] = f2bf(rm);
      }
    }
  }
  __syncthreads();

  // ---- Phase 9: res = rm @ fc2 + b + query_f ----
  {
    floatx4 acc[2];
    acc[0] = zero4; acc[1] = zero4;
    #pragma unroll 2
    for (int ks = 0; ks < 8; ++ks) {
      short8 af = *(const short8*)&s_rm[lm*264 + ks*32 + lq*8];
      #pragma unroll
      for (int c = 0; c < 2; ++c) {
        int col = (w*2 + c)*16 + lm;
        short8 bf = *(const short8*)&fc2_t[(size_t)col*256 + ks*32 + lq*8];
        acc[c] = __builtin_amdgcn_mfma_f32_16x16x32_bf16(af, bf, acc[c], 0, 0, 0);
      }
    }
    if (lq == 0) {
      #pragma unroll
      for (int c = 0; c < 2; ++c) {
        int col = (w*2 + c)*16 + lm;
        float bias = fc2_b[col];
        #pragma unroll
        for (int r = 0; r < 4; ++r) {
          float res = acc[c][r] + bias + query[(size_t)(bm0 + r)*QROW + 3 + col];
          __builtin_nontemporal_store(res, &out_res[(size_t)(bm0 + r)*DP + col]);
        }
      }
    }
  }
}

extern "C" void kernel_launch(void* const* d_in, const int* in_sizes, int n_in,
                              void* d_out, int out_size, void* d_ws, size_t ws_size,
                              hipStream_t stream) {
  const float* xyz      = (const float*)d_in[0];
  const float* features = (const float*)d_in[1];
  const float* query    = (const float*)d_in[2];
  const float* fc1_w    = (const float*)d_in[3];
  const float* fc1_b    = (const float*)d_in[4];
  const float* fc2_w    = (const float*)d_in[5];
  const float* fc2_b    = (const float*)d_in[6];
  const float* d1_w     = (const float*)d_in[7];
  const float* d1_b     = (const float*)d_in[8];
  const float* d2_w     = (const float*)d_in[9];
  const float* d2_b     = (const float*)d_in[10];
  const float* g1_w     = (const float*)d_in[11];
  const float* g1_b     = (const float*)d_in[12];
  const float* g2_w     = (const float*)d_in[13];
  const float* g2_b     = (const float*)d_in[14];
  const float* wq       = (const float*)d_in[15];
  const float* wk       = (const float*)d_in[16];
  const float* wv       = (const float*)d_in[17];

  int* knn = (int*)d_ws;                                          // 512 KB
  unsigned short* wT = (unsigned short*)((char*)d_ws + 524288);   // 832 KB bf16
  float* out_res  = (float*)d_out;
  float* out_attn = (float*)d_out + (size_t)BB*MM*DP;

  prep_weights<<<1664, 256, 0, stream>>>(wq, fc1_w, wk, wv, d2_w, g1_w, g2_w, fc2_w, wT);
  knn_kernel<<<1024, 256, 0, stream>>>(xyz, query, knn);
  fused_mfma<<<BB*MM/4, 256, 0, stream>>>(
      xyz, features, query, fc1_b, fc2_b, d1_w, d1_b, d2_b, g1_b, g2_b,
      wT, knn, out_res, out_attn);
}

// Round 6
// 475.174 us; speedup vs baseline: 1.7395x; 1.7395x over previous
//
#include <hip/hip_runtime.h>
#include <cstdint>
#include <cstddef>

#define BB 4
#define NN 8192
#define MM 2048
#define KK 16
#define DP 128
#define DM 256
#define QROW 131   // 3 + 128 floats per query row
#define CAP3 128   // per-query candidate capacity (E[cand]~30)

typedef __attribute__((ext_vector_type(8))) short short8;
typedef __attribute__((ext_vector_type(4))) float floatx4;

__device__ __forceinline__ unsigned short f2bf(float x) {
  unsigned u = __float_as_uint(x);
  unsigned r = (u + 0x7FFFu + ((u >> 16) & 1u)) >> 16;   // RNE
  return (unsigned short)r;
}

// Deterministic distance->sortable-key. Same DAG everywhere (harness-verified
// across r2-r5): orders identically to the reference dist for selection.
__device__ __forceinline__ unsigned dkey(float qx, float qy, float qz, float q2,
                                         float xx, float xy, float xz, float x2) {
  float cr = fmaf(qz, xz, fmaf(qy, xy, qx * xx));
  float d  = fmaf(-2.0f, cr, q2 + x2);
  unsigned u = __float_as_uint(d);
  return (u & 0x80000000u) ? ~u : (u | 0x80000000u);  // ascending-sortable
}

// Cross-lane bitonic sort of 64 u32 values (one per lane), ascending by lane.
// 21 compare-exchange stages.
__device__ __forceinline__ unsigned sort64(unsigned v, int l) {
  #pragma unroll
  for (int k = 2; k <= 64; k <<= 1) {
    #pragma unroll
    for (int j = k >> 1; j >= 1; j >>= 1) {
      unsigned o = (unsigned)__shfl_xor((int)v, j, 64);
      bool dirUp = ((l & k) == 0);      // k=64: all ascending
      bool upper = ((l & j) != 0);
      unsigned mn = v < o ? v : o, mx = v < o ? o : v;
      v = (dirUp == upper) ? mx : mn;
    }
  }
  return v;
}

// ---------------------------------------------------------------------------
// Kernel 0: weights f32->bf16, transposed to [N][K] (k-contig) back-to-back.
// wk stored NEGATED so fused computes a = (q + pe) + x@(-wk) in one MFMA
// accumulation (bounds concurrent accumulators; pe dies into the a-init).
// ---------------------------------------------------------------------------
__global__ __launch_bounds__(256) void prep_weights(
    const float* __restrict__ wq, const float* __restrict__ fc1,
    const float* __restrict__ wk, const float* __restrict__ wv,
    const float* __restrict__ d2, const float* __restrict__ g1,
    const float* __restrict__ g2, const float* __restrict__ fc2,
    unsigned short* __restrict__ dst)
{
  long e = (long)blockIdx.x * 256 + threadIdx.x;
  if (e >= 425984) return;
  const float* src; int sh; int Nmat; long off; bool neg = false;
  if (e < 32768)       { src = wq;  sh = 7; Nmat = 256; off = 0; }
  else if (e < 65536)  { src = fc1; sh = 7; Nmat = 256; off = 32768; }
  else if (e < 131072) { src = wk;  sh = 8; Nmat = 256; off = 65536; neg = true; }
  else if (e < 196608) { src = wv;  sh = 8; Nmat = 256; off = 131072; }
  else if (e < 262144) { src = d2;  sh = 8; Nmat = 256; off = 196608; }
  else if (e < 327680) { src = g1;  sh = 8; Nmat = 256; off = 262144; }
  else if (e < 393216) { src = g2;  sh = 8; Nmat = 256; off = 327680; }
  else                 { src = fc2; sh = 8; Nmat = 128; off = 393216; }
  long d = e - off;
  int K = 1 << sh;
  int n = (int)(d >> sh), k = (int)(d & (K - 1));
  float v = src[(long)k * Nmat + n];
  dst[e] = f2bf(neg ? -v : v);
}

// ---------------------------------------------------------------------------
// Kernel 1: exact KNN (k=16) — LANE-MIN THRESHOLD version. No per-point data
// structure (r5's register arrays were demoted to scratch: VGPR=48, 70%
// stall), no barriers, no histograms.
// Pass 1: lane-private streaming min over 128 points (per query, 2 q/wave).
//   Bitonic-sort the 64 lane-mins; T = 16th smallest. The 16 smallest
//   lane-mins are 16 DISTINCT points <= T => population 16th <= T =>
//   {u <= T} is an exact superset of the true top-16 (and >= 16 elems).
// Pass 2: re-scan (L2-warm), push composites (key<<32|idx) to wave-private
//   LDS rows (E[cnt]~30, CAP 128).
// Select: 16 butterfly-min rounds over 2 regs/lane; composite order ==
//   jax.lax.top_k tie semantics. cnt>CAP (prob ~0) -> exact exclusion scan.
// ---------------------------------------------------------------------------
__global__ __launch_bounds__(256, 4) void knn_kernel(
    const float* __restrict__ xyz, const float* __restrict__ query,
    int* __restrict__ knn_out)
{
  __shared__ unsigned long long cand[8][CAP3];   // 8 KB, wave-private rows
  __shared__ int s_cnt[8];

  const int tid = threadIdx.x;
  const int l = tid & 63, w = tid >> 6;
  const int qbase = (blockIdx.x * 4 + w) * 2;   // two queries per wave
  const int b = qbase >> 11;                    // pairs never straddle batches
  const float* X = xyz + (size_t)b * NN * 3;

  float qx[2], qy[2], qz[2], q2[2];
  #pragma unroll
  for (int q = 0; q < 2; ++q) {
    const float* qp = query + (size_t)(qbase + q) * QROW;
    qx[q] = qp[0]; qy[q] = qp[1]; qz[q] = qp[2];
    q2[q] = fmaf(qz[q], qz[q], fmaf(qy[q], qy[q], qx[q] * qx[q]));
  }

  if (l < 2) s_cnt[w*2 + l] = 0;   // wave-own row init; DS-ordered per wave

  // ---- Pass 1: lane-private streaming min (no arrays) ----
  unsigned m0 = 0xFFFFFFFFu, m1 = 0xFFFFFFFFu;
  #pragma unroll 2
  for (int it = 0; it < NN / 256; ++it) {       // 32 iterations
    int p0 = it * 256 + l * 4;                  // 4 points per lane
    const float4* P = (const float4*)(X + 3 * p0);   // 48-B lane stride, 16-B aligned
    float4 A = P[0], Bv = P[1], C = P[2];
    float px[4] = {A.x, A.w, Bv.z, C.y};
    float py[4] = {A.y, Bv.x, Bv.w, C.z};
    float pz[4] = {A.z, Bv.y, C.x, C.w};
    #pragma unroll
    for (int j = 0; j < 4; ++j) {
      float x2 = fmaf(pz[j], pz[j], fmaf(py[j], py[j], px[j] * px[j]));
      unsigned u0 = dkey(qx[0], qy[0], qz[0], q2[0], px[j], py[j], pz[j], x2);
      m0 = u0 < m0 ? u0 : m0;
      unsigned u1 = dkey(qx[1], qy[1], qz[1], q2[1], px[j], py[j], pz[j], x2);
      m1 = u1 < m1 ? u1 : m1;
    }
  }
  const unsigned T0 = (unsigned)__shfl((int)sort64(m0, l), 15, 64);
  const unsigned T1 = (unsigned)__shfl((int)sort64(m1, l), 15, 64);

  // ---- Pass 2: filtered re-scan, push candidates ----
  #pragma unroll 2
  for (int it = 0; it < NN / 256; ++it) {
    int p0 = it * 256 + l * 4;
    const float4* P = (const float4*)(X + 3 * p0);
    float4 A = P[0], Bv = P[1], C = P[2];
    float px[4] = {A.x, A.w, Bv.z, C.y};
    float py[4] = {A.y, Bv.x, Bv.w, C.z};
    float pz[4] = {A.z, Bv.y, C.x, C.w};
    #pragma unroll
    for (int j = 0; j < 4; ++j) {
      float x2 = fmaf(pz[j], pz[j], fmaf(py[j], py[j], px[j] * px[j]));
      unsigned idx = (unsigned)(p0 + j);
      unsigned u0 = dkey(qx[0], qy[0], qz[0], q2[0], px[j], py[j], pz[j], x2);
      if (u0 <= T0) {
        int p = atomicAdd(&s_cnt[w*2], 1);
        if (p < CAP3) cand[w*2][p] = ((unsigned long long)u0 << 32) | idx;
      }
      unsigned u1 = dkey(qx[1], qy[1], qz[1], q2[1], px[j], py[j], pz[j], x2);
      if (u1 <= T1) {
        int p = atomicAdd(&s_cnt[w*2 + 1], 1);
        if (p < CAP3) cand[w*2 + 1][p] = ((unsigned long long)u1 << 32) | idx;
      }
    }
  }

  // ---- Select per query (wave-private; no barriers anywhere) ----
  #pragma unroll
  for (int q = 0; q < 2; ++q) {
    const int qs = w*2 + q;
    const int cnt = s_cnt[qs];          // own-wave atomics, DS-ordered
    if (cnt <= CAP3) {
      unsigned long long v[CAP3 / 64];
      #pragma unroll
      for (int i = 0; i < CAP3/64; ++i) {
        int p = i*64 + l;
        v[i] = (p < cnt) ? cand[qs][p] : ~0ull;
      }
      for (int r = 0; r < KK; ++r) {
        unsigned long long m = v[0] < v[1] ? v[0] : v[1];
        #pragma unroll
        for (int d = 32; d >= 1; d >>= 1) {
          unsigned long long o = __shfl_xor(m, d, 64);
          m = o < m ? o : m;
        }
        if (l == 0) knn_out[(qbase + q)*KK + r] = (int)(unsigned)(m & 0xffffffffu);
        #pragma unroll
        for (int i = 0; i < CAP3/64; ++i) if (v[i] == m) v[i] = ~0ull;
      }
    } else {
      // ---- Fallback (prob ~0): 16 ascending rounds, composite exclusion ----
      unsigned long long last = 0;
      for (int r = 0; r < KK; ++r) {
        unsigned long long best = ~0ull;
        for (int n = l; n < NN; n += 64) {
          float xx = X[3*n], xy = X[3*n + 1], xz = X[3*n + 2];
          float x2 = fmaf(xz, xz, fmaf(xy, xy, xx * xx));
          unsigned u = dkey(qx[q], qy[q], qz[q], q2[q], xx, xy, xz, x2);
          unsigned long long comp = ((unsigned long long)u << 32) | (unsigned)n;
          if (comp > last && comp < best) best = comp;
        }
        #pragma unroll
        for (int d = 32; d >= 1; d >>= 1) {
          unsigned long long o = __shfl_xor(best, d, 64);
          best = o < best ? o : best;
        }
        last = best;
        if (l == 0) knn_out[(qbase + q)*KK + r] = (int)(unsigned)(best & 0xffffffffu);
      }
    }
  }
}

// ---------------------------------------------------------------------------
// Balanced MFMA tile-GEMM helper. ks-loop at UNROLL 2 bounds in-flight
// staging registers (full unroll -> scheduler hoists ~32 global loads ->
// spill; proven r2->r3: WRITE 352->185 MB).
// ---------------------------------------------------------------------------
template<int KT, int RT>
__device__ __forceinline__ void gemm_tiles(
    const unsigned short* aBase, int aStride,
    const unsigned short* __restrict__ bT,
    int lm, int lq, int colBase, int rtBase, floatx4 (&acc)[RT][4])
{
  const unsigned short* aRow = aBase + (rtBase*16 + lm)*aStride + lq*8;
  const unsigned short* bRow = bT + (size_t)(colBase + lm)*(KT*32) + lq*8;
  #pragma unroll 2
  for (int ks = 0; ks < KT; ++ks) {
    short8 af[RT];
    #pragma unroll
    for (int rt = 0; rt < RT; ++rt)
      af[rt] = *(const short8*)&aRow[rt*16*aStride + ks*32];
    short8 bf[4];
    #pragma unroll
    for (int c = 0; c < 4; ++c)
      bf[c] = *(const short8*)&bRow[(size_t)c*16*(KT*32) + ks*32];
    #pragma unroll
    for (int rt = 0; rt < RT; ++rt)
      #pragma unroll
      for (int c = 0; c < 4; ++c)
        acc[rt][c] = __builtin_amdgcn_mfma_f32_16x16x32_bf16(af[rt], bf[c], acc[rt][c], 0, 0, 0);
  }
}

// ---------------------------------------------------------------------------
// Kernel 2: fused block, 4 queries (64 rows) per 256-thread WG, 2 blocks/CU.
// Unchanged from r4 (271 us, VGPR=100, no bulk spill).
// ---------------------------------------------------------------------------
__global__ __launch_bounds__(256, 2) void fused_mfma(
    const float* __restrict__ xyz, const float* __restrict__ features,
    const float* __restrict__ query,
    const float* __restrict__ fc1_b, const float* __restrict__ fc2_b,
    const float* __restrict__ d1_w,  const float* __restrict__ d1_b,
    const float* __restrict__ d2_b,
    const float* __restrict__ g1_b,  const float* __restrict__ g2_b,
    const unsigned short* __restrict__ wT,
    const int* __restrict__ knn_idx,
    float* __restrict__ out_res, float* __restrict__ out_attn)
{
  const unsigned short* wq_t  = wT;
  const unsigned short* fc1_t = wT + 32768;
  const unsigned short* wkN_t = wT + 65536;    // negated
  const unsigned short* wv_t  = wT + 131072;
  const unsigned short* d2_t  = wT + 196608;
  const unsigned short* g1_t  = wT + 262144;
  const unsigned short* g2_t  = wT + 327680;
  const unsigned short* fc2_t = wT + 393216;

  __shared__ alignas(16) unsigned short bufA[64*264];  // feat(136) / h1 / a / rm
  __shared__ alignas(16) unsigned short bufB[64*264];  // x / h
  __shared__ alignas(16) unsigned short s_qf[16*136];  // query_f bf16 (rows 0..3)
  __shared__ alignas(16) float s_q[4*256];             // q projection (f32)
  __shared__ float s_delta[64][4];
  __shared__ int   s_idx[64];

  const int tid = threadIdx.x;
  const int l  = tid & 63, w = tid >> 6;
  const int lm = l & 15,  lq = l >> 4;
  const int colBase = w * 64;
  const int bm0 = blockIdx.x << 2;
  const int b   = bm0 >> 11;

  // ---- Phase 0: indices, delta, query_f, feature gather ----
  if (tid < 64) {
    int q = tid >> 4, n = tid & 15;
    int idx = knn_idx[(bm0 + q)*KK + n];
    s_idx[tid] = idx;
    const float* qp = query + (size_t)(bm0 + q) * QROW;
    const float* xp = xyz + ((size_t)b*NN + idx)*3;
    s_delta[tid][0] = qp[0] - xp[0];
    s_delta[tid][1] = qp[1] - xp[1];
    s_delta[tid][2] = qp[2] - xp[2];
  }
  {
    int e = tid * 2;                    // 512 elems: rows 0..3 x 128 cols
    int q = e >> 7, c = e & 127;
    const float* qp = query + (size_t)(bm0 + q)*QROW + 3 + c;
    unsigned v = ((unsigned)f2bf(qp[1]) << 16) | f2bf(qp[0]);
    *(unsigned*)&s_qf[q*136 + c] = v;
  }
  __syncthreads();
  {
    int r = tid >> 2, c0 = (tid & 3) * 32;
    const float4* fp4 = (const float4*)(features + ((size_t)b*NN + s_idx[r])*DP + c0);
    unsigned short* dst = &bufA[r*136 + c0];
    #pragma unroll
    for (int i = 0; i < 8; ++i) {
      float4 v4 = fp4[i];
      *(unsigned*)&dst[i*4]     = ((unsigned)f2bf(v4.y) << 16) | f2bf(v4.x);
      *(unsigned*)&dst[i*4 + 2] = ((unsigned)f2bf(v4.w) << 16) | f2bf(v4.z);
    }
  }
  __syncthreads();

  const floatx4 zero4 = {0.f, 0.f, 0.f, 0.f};

  // ---- Phase 1: x = feat @ fc1 + b  -> bufB ;  q = qf @ wq -> s_q ----
  {
    floatx4 acc[4][4];
    #pragma unroll
    for (int rt = 0; rt < 4; ++rt)
      #pragma unroll
      for (int c = 0; c < 4; ++c) acc[rt][c] = zero4;
    gemm_tiles<4,4>(bufA, 136, fc1_t, lm, lq, colBase, 0, acc);
    #pragma unroll
    for (int c = 0; c < 4; ++c) {
      float bias = fc1_b[colBase + c*16 + lm];
      #pragma unroll
      for (int rt = 0; rt < 4; ++rt)
        #pragma unroll
        for (int r = 0; r < 4; ++r)
          bufB[(rt*16 + lq*4 + r)*264 + colBase + c*16 + lm] = f2bf(acc[rt][c][r] + bias);
    }
  }
  {
    floatx4 qa[1][4];
    #pragma unroll
    for (int c = 0; c < 4; ++c) qa[0][c] = zero4;
    gemm_tiles<4,1>(s_qf, 136, wq_t, lm, lq, colBase, 0, qa);
    if (lq == 0) {
      #pragma unroll
      for (int c = 0; c < 4; ++c)
        #pragma unroll
        for (int r = 0; r < 4; ++r)
          s_q[r*256 + colBase + c*16 + lm] = qa[0][c][r];   // row r == query r
    }
  }
  __syncthreads();   // x visible; bufA(feat) dead

  // ---- Phase 2: h1 = relu(delta @ d1 + b) -> bufA (VALU, tiny K=3) ----
  {
    int c = tid;
    float w0 = d1_w[c], w1 = d1_w[256 + c], w2 = d1_w[512 + c], bb = d1_b[c];
    #pragma unroll 4
    for (int r = 0; r < 64; ++r) {
      float v = fmaf(s_delta[r][2], w2, fmaf(s_delta[r][1], w1,
                fmaf(s_delta[r][0], w0, bb)));
      bufA[r*264 + c] = f2bf(v > 0.f ? v : 0.f);
    }
  }
  __syncthreads();   // h1 visible

  // ---- Phase 3: pe = h1 @ d2 + b (regs; acc set #1) ----
  floatx4 pe[4][4];
  #pragma unroll
  for (int rt = 0; rt < 4; ++rt)
    #pragma unroll
    for (int c = 0; c < 4; ++c) pe[rt][c] = zero4;
  gemm_tiles<8,4>(bufA, 264, d2_t, lm, lq, colBase, 0, pe);
  #pragma unroll
  for (int c = 0; c < 4; ++c) {
    float bias = d2_b[colBase + c*16 + lm];
    #pragma unroll
    for (int rt = 0; rt < 4; ++rt)
      #pragma unroll
      for (int r = 0; r < 4; ++r) pe[rt][c][r] += bias;
  }

  // ---- Phase 4: vpe = x @ wv + pe (acc set #2 initialized from pe) ----
  floatx4 vpe[4][4];
  #pragma unroll
  for (int rt = 0; rt < 4; ++rt)
    #pragma unroll
    for (int c = 0; c < 4; ++c) vpe[rt][c] = pe[rt][c];
  gemm_tiles<8,4>(bufB, 264, wv_t, lm, lq, colBase, 0, vpe);
  __syncthreads();   // all waves done reading bufA(h1); a-writes may begin

  // ---- Phase 5: a = (q + pe) + x @ (-wk) -> bufA ; pe dies in the init ----
  {
    floatx4 acc[4][4];
    #pragma unroll
    for (int rt = 0; rt < 4; ++rt)
      #pragma unroll
      for (int c = 0; c < 4; ++c) {
        float qv = s_q[rt*256 + colBase + c*16 + lm];
        #pragma unroll
        for (int r = 0; r < 4; ++r) acc[rt][c][r] = qv + pe[rt][c][r];
      }
    gemm_tiles<8,4>(bufB, 264, wkN_t, lm, lq, colBase, 0, acc);
    #pragma unroll
    for (int rt = 0; rt < 4; ++rt)
      #pragma unroll
      for (int c = 0; c < 4; ++c)
        #pragma unroll
        for (int r = 0; r < 4; ++r)
          bufA[(rt*16 + lq*4 + r)*264 + colBase + c*16 + lm] = f2bf(acc[rt][c][r]);
  }
  __syncthreads();   // a visible; bufB(x) dead

  // ---- Phase 6: h = relu(a @ g1 + b) -> bufB ----
  {
    floatx4 h[4][4];
    #pragma unroll
    for (int rt = 0; rt < 4; ++rt)
      #pragma unroll
      for (int c = 0; c < 4; ++c) h[rt][c] = zero4;
    gemm_tiles<8,4>(bufA, 264, g1_t, lm, lq, colBase, 0, h);
    #pragma unroll
    for (int c = 0; c < 4; ++c) {
      float bias = g1_b[colBase + c*16 + lm];
      #pragma unroll
      for (int rt = 0; rt < 4; ++rt)
        #pragma unroll
        for (int r = 0; r < 4; ++r) {
          float v = h[rt][c][r] + bias;
          bufB[(rt*16 + lq*4 + r)*264 + colBase + c*16 + lm] = f2bf(v > 0.f ? v : 0.f);
        }
    }
  }
  __syncthreads();   // h visible; bufA(a) dead -> reuse as s_rm

  // ---- Phase 7/8: lg = h @ g2 + b (all rt in ONE gemm: B loaded once),
  //      softmax over neighbors, NT attn store, rm = sum_n attn * vpe ----
  unsigned short* s_rm = bufA;   // [16][264], rows 0..3 valid
  {
    floatx4 lg[4][4];
    #pragma unroll
    for (int rt = 0; rt < 4; ++rt)
      #pragma unroll
      for (int c = 0; c < 4; ++c) lg[rt][c] = zero4;
    gemm_tiles<8,4>(bufB, 264, g2_t, lm, lq, colBase, 0, lg);
    #pragma unroll
    for (int rt = 0; rt < 4; ++rt) {
      #pragma unroll
      for (int c = 0; c < 4; ++c) {
        float bias = g2_b[colBase + c*16 + lm];
        float v[4];
        float mx = -INFINITY;
        #pragma unroll
        for (int r = 0; r < 4; ++r) {
          v[r] = (lg[rt][c][r] + bias) * 0.0625f;
          mx = fmaxf(mx, v[r]);
        }
        mx = fmaxf(mx, __shfl_xor(mx, 16, 64));
        mx = fmaxf(mx, __shfl_xor(mx, 32, 64));
        float s = 0.f;
        #pragma unroll
        for (int r = 0; r < 4; ++r) { v[r] = __expf(v[r] - mx); s += v[r]; }
        s += __shfl_xor(s, 16, 64);
        s += __shfl_xor(s, 32, 64);
        float inv = 1.0f / s;
        float rm = 0.f;
        size_t abase = ((size_t)(bm0 + rt)*KK)*DM + colBase + c*16 + lm;
        #pragma unroll
        for (int r = 0; r < 4; ++r) {
          float at = v[r] * inv;
          __builtin_nontemporal_store(at, &out_attn[abase + (size_t)(lq*4 + r)*DM]);
          rm = fmaf(at, vpe[rt][c][r], rm);
        }
        rm += __shfl_xor(rm, 16, 64);
        rm += __shfl_xor(rm, 32, 64);
        if (lq == 0) s_rm[rt*264 + colBase + c*16 + lm] = f2bf(rm);
      }
    }
  }
  __syncthreads();

  // ---- Phase 9: res = rm @ fc2 + b + query_f ----
  {
    floatx4 acc[2];
    acc[0] = zero4; acc[1] = zero4;
    #pragma unroll 2
    for (int ks = 0; ks < 8; ++ks) {
      short8 af = *(const short8*)&s_rm[lm*264 + ks*32 + lq*8];
      #pragma unroll
      for (int c = 0; c < 2; ++c) {
        int col = (w*2 + c)*16 + lm;
        short8 bf = *(const short8*)&fc2_t[(size_t)col*256 + ks*32 + lq*8];
        acc[c] = __builtin_amdgcn_mfma_f32_16x16x32_bf16(af, bf, acc[c], 0, 0, 0);
      }
    }
    if (lq == 0) {
      #pragma unroll
      for (int c = 0; c < 2; ++c) {
        int col = (w*2 + c)*16 + lm;
        float bias = fc2_b[col];
        #pragma unroll
        for (int r = 0; r < 4; ++r) {
          float res = acc[c][r] + bias + query[(size_t)(bm0 + r)*QROW + 3 + col];
          __builtin_nontemporal_store(res, &out_res[(size_t)(bm0 + r)*DP + col]);
        }
      }
    }
  }
}

extern "C" void kernel_launch(void* const* d_in, const int* in_sizes, int n_in,
                              void* d_out, int out_size, void* d_ws, size_t ws_size,
                              hipStream_t stream) {
  const float* xyz      = (const float*)d_in[0];
  const float* features = (const float*)d_in[1];
  const float* query    = (const float*)d_in[2];
  const float* fc1_w    = (const float*)d_in[3];
  const float* fc1_b    = (const float*)d_in[4];
  const float* fc2_w    = (const float*)d_in[5];
  const float* fc2_b    = (const float*)d_in[6];
  const float* d1_w     = (const float*)d_in[7];
  const float* d1_b     = (const float*)d_in[8];
  const float* d2_w     = (const float*)d_in[9];
  const float* d2_b     = (const float*)d_in[10];
  const float* g1_w     = (const float*)d_in[11];
  const float* g1_b     = (const float*)d_in[12];
  const float* g2_w     = (const float*)d_in[13];
  const float* g2_b     = (const float*)d_in[14];
  const float* wq       = (const float*)d_in[15];
  const float* wk       = (const float*)d_in[16];
  const float* wv       = (const float*)d_in[17];

  int* knn = (int*)d_ws;                                          // 512 KB
  unsigned short* wT = (unsigned short*)((char*)d_ws + 524288);   // 832 KB bf16
  float* out_res  = (float*)d_out;
  float* out_attn = (float*)d_out + (size_t)BB*MM*DP;

  prep_weights<<<1664, 256, 0, stream>>>(wq, fc1_w, wk, wv, d2_w, g1_w, g2_w, fc2_w, wT);
  knn_kernel<<<1024, 256, 0, stream>>>(xyz, query, knn);
  fused_mfma<<<BB*MM/4, 256, 0, stream>>>(
      xyz, features, query, fc1_b, fc2_b, d1_w, d1_b, d2_b, g1_b, g2_b,
      wT, knn, out_res, out_attn);
}